// Round 3
// baseline (218.065 us; speedup 1.0000x reference)
//
#include <hip/hip_runtime.h>
#include <hip/hip_bf16.h>
#include <stdint.h>

// CortexBlock — reference collapses (U,V start at 0 and the update is
// multiplicative in the state, so the fast-weight path is identically 0):
//   y[row,h,:] = sigmoid((q_h.k_h)/8) * v_h ;  out = y @ Wo^T
// Pipeline: cast (X,W -> bf16) -> QKV GEMM (m97-style async-LDS MFMA)
//        -> score S = sigmoid(qk/8) -> out GEMM with s*v fused into A-staging.
#define D_MODEL 1024
#define N_HEADS 16
#define D_HEAD  64
#define SEQ_T   2048
#define BATCH   4

typedef unsigned short u16;
typedef __bf16 bf16x8 __attribute__((ext_vector_type(8)));
typedef float  f32x4  __attribute__((ext_vector_type(4)));

// ---- helpers ---------------------------------------------------------------
__device__ __forceinline__ u16 f2bf(float x) {  // RNE f32->bf16
  unsigned u = __float_as_uint(x);
  u += 0x7fffu + ((u >> 16) & 1u);
  return (u16)(u >> 16);
}
__device__ __forceinline__ unsigned pk2(float a, float b) {
  return (unsigned)f2bf(a) | ((unsigned)f2bf(b) << 16);
}
__device__ __forceinline__ void bf8_to_f32(uint4 u, float* f) {
  f[0] = __uint_as_float(u.x << 16); f[1] = __uint_as_float(u.x & 0xffff0000u);
  f[2] = __uint_as_float(u.y << 16); f[3] = __uint_as_float(u.y & 0xffff0000u);
  f[4] = __uint_as_float(u.z << 16); f[5] = __uint_as_float(u.z & 0xffff0000u);
  f[6] = __uint_as_float(u.w << 16); f[7] = __uint_as_float(u.w & 0xffff0000u);
}
// async global->LDS, 16B per lane; LDS dest is wave-uniform base + lane*16.
__device__ __forceinline__ void cp16(const u16* g, u16* l) {
  __builtin_amdgcn_global_load_lds(
      (const __attribute__((address_space(1))) unsigned int*)g,
      (__attribute__((address_space(3))) unsigned int*)l, 16, 0, 0);
}
__device__ __forceinline__ unsigned scale2(unsigned p, float s) {
  float lo = __uint_as_float(p << 16) * s;
  float hi = __uint_as_float(p & 0xffff0000u) * s;
  return pk2(lo, hi);
}

// ---- fused cast fp32 -> bf16 (X then Wq|Wk|Wv|Wo) --------------------------
__global__ __launch_bounds__(256) void cast_kernel(const float* __restrict__ hs,
                                                   const float* __restrict__ wq,
                                                   const float* __restrict__ wk,
                                                   const float* __restrict__ wv,
                                                   const float* __restrict__ wo,
                                                   u16* __restrict__ Xb,
                                                   u16* __restrict__ Wb) {
  int i = blockIdx.x * 256 + threadIdx.x;  // float4 units, 3M total
  const float* src; u16* dst; int off;
  if (i < (2 << 20)) { src = hs; dst = Xb; off = i; }
  else {
    int j = i - (2 << 20);
    int which = j >> 18;                   // block-uniform
    const float* srcs[4] = {wq, wk, wv, wo};
    src = srcs[which]; dst = Wb + ((size_t)which << 20); off = j & 0x3ffff;
  }
  float4 v = ((const float4*)src)[off];
  uint2 o; o.x = pk2(v.x, v.y); o.y = pk2(v.z, v.w);
  ((uint2*)dst)[off] = o;
}

// ---- bf16 MFMA GEMM: C[M,N] = A[M,K(lda)] * B[N,K]^T -----------------------
// 128x128 tile, 4 waves (2x2 of 64x64), BK=32, mfma_f32_16x16x32_bf16.
// LDS: unpadded 128x32, XOR chunk swizzle (chunk = gchunk ^ ((row>>1)&3)) so
// fragment ds_read_b128s are 2-way (free) while global_load_lds keeps its
// required base+lane*16 destination. FUSE_SCALE: A = S[row,head]*A (reg path).
template <bool STORE_BF16, bool FUSE_SCALE>
__global__ __launch_bounds__(256) void gemm_bt_kernel(const u16* __restrict__ A,
                                                      const u16* __restrict__ B,
                                                      const float* __restrict__ S,
                                                      void* __restrict__ Cptr,
                                                      int M, int N, int K, int lda) {
  __shared__ u16 As[128 * 32];
  __shared__ u16 Bs[128 * 32];
  const int tid  = threadIdx.x;
  const int lane = tid & 63;
  const int wave = tid >> 6;
  const int wm = (wave >> 1) * 64;
  const int wn = (wave & 1) * 64;
  const int bm = blockIdx.y * 128;
  const int bn = blockIdx.x * 128;
  const int quad = lane >> 4;
  const int l16  = lane & 15;

  // async staging: wave stages 16 rows/instr; lane -> row base+(l>>2),
  // LDS chunk l&3, global chunk (l&3)^((l>>3)&3)  (g(row)=(row>>1)&3).
  const int srow   = lane >> 2;
  const int gchunk = (lane & 3) ^ ((lane >> 3) & 3);
  // fragment read chunk: quad ^ g(row) = quad ^ ((l16>>1)&3), per-lane const.
  const int rchunk = quad ^ ((l16 >> 1) & 3);

  const u16* Bg0 = B + (size_t)(bn + wave * 16 + srow) * K + gchunk * 8;
  const u16* Bg1 = Bg0 + (size_t)64 * K;
  u16* Bl0 = Bs + wave * 16 * 32 + lane * 8;
  u16* Bl1 = Bl0 + 64 * 32;

  const u16* Ag0 = A + (size_t)(bm + wave * 16 + srow) * lda + gchunk * 8;
  const u16* Ag1 = Ag0 + (size_t)64 * lda;
  u16* Al0 = As + wave * 16 * 32 + lane * 8;
  u16* Al1 = Al0 + 64 * 32;

  // register-staging path (FUSE_SCALE): thread -> rows lr, lr+64, chunk tid&3
  const int lr = tid >> 2;
  const int lch = tid & 3;
  const u16* Arp0 = A + (size_t)(bm + lr) * lda + lch * 8;
  const u16* Arp1 = A + (size_t)(bm + lr + 64) * lda + lch * 8;
  const int wch = lch ^ ((lr >> 1) & 3);
  u16* Awp0 = As + lr * 32 + wch * 8;
  u16* Awp1 = As + (lr + 64) * 32 + wch * 8;
  const float* Sp0 = S + (size_t)(bm + lr) * N_HEADS;
  const float* Sp1 = S + (size_t)(bm + lr + 64) * N_HEADS;

  f32x4 acc[4][4];
  #pragma unroll
  for (int i = 0; i < 4; ++i)
    #pragma unroll
    for (int j = 0; j < 4; ++j) acc[i][j] = (f32x4){0.f, 0.f, 0.f, 0.f};

  uint4 ra0, ra1; float rs0, rs1;
  if (FUSE_SCALE) {
    ra0 = *(const uint4*)Arp0; ra1 = *(const uint4*)Arp1;
    rs0 = Sp0[0]; rs1 = Sp1[0];
  }

  for (int k0 = 0; k0 < K; k0 += 32) {
    __syncthreads();
    if (FUSE_SCALE) {
      uint4 w0, w1;
      w0.x = scale2(ra0.x, rs0); w0.y = scale2(ra0.y, rs0);
      w0.z = scale2(ra0.z, rs0); w0.w = scale2(ra0.w, rs0);
      w1.x = scale2(ra1.x, rs1); w1.y = scale2(ra1.y, rs1);
      w1.z = scale2(ra1.z, rs1); w1.w = scale2(ra1.w, rs1);
      *(uint4*)Awp0 = w0;
      *(uint4*)Awp1 = w1;
    } else {
      cp16(Ag0 + k0, Al0);
      cp16(Ag1 + k0, Al1);
    }
    cp16(Bg0 + k0, Bl0);
    cp16(Bg1 + k0, Bl1);
    __syncthreads();
    if (FUSE_SCALE && k0 + 32 < K) {  // prefetch next A chunk during MFMA
      ra0 = *(const uint4*)(Arp0 + k0 + 32);
      ra1 = *(const uint4*)(Arp1 + k0 + 32);
      rs0 = Sp0[(k0 + 32) >> 6]; rs1 = Sp1[(k0 + 32) >> 6];
    }
    bf16x8 af[4], bfr[4];
    #pragma unroll
    for (int i = 0; i < 4; ++i)
      af[i] = *(const bf16x8*)(As + (wm + i * 16 + l16) * 32 + rchunk * 8);
    #pragma unroll
    for (int j = 0; j < 4; ++j)
      bfr[j] = *(const bf16x8*)(Bs + (wn + j * 16 + l16) * 32 + rchunk * 8);
    #pragma unroll
    for (int i = 0; i < 4; ++i)
      #pragma unroll
      for (int j = 0; j < 4; ++j)
        acc[i][j] = __builtin_amdgcn_mfma_f32_16x16x32_bf16(af[i], bfr[j], acc[i][j], 0, 0, 0);
  }

  // epilogue: C/D layout col=lane&15, row=quad*4+reg
  #pragma unroll
  for (int i = 0; i < 4; ++i) {
    #pragma unroll
    for (int j = 0; j < 4; ++j) {
      #pragma unroll
      for (int e = 0; e < 4; ++e) {
        int row = bm + wm + i * 16 + quad * 4 + e;
        int col = bn + wn + j * 16 + l16;
        if (STORE_BF16)
          ((u16*)Cptr)[(size_t)row * N + col] = f2bf(acc[i][j][e]);
        else
          ((float*)Cptr)[(size_t)row * N + col] = acc[i][j][e];
      }
    }
  }
}

// ---- S[row,h] = sigmoid(dot(q_h,k_h)/8) ------------------------------------
__global__ __launch_bounds__(256) void score_kernel(const u16* __restrict__ QKV,
                                                    float* __restrict__ S) {
  int tid = blockIdx.x * 256 + threadIdx.x;  // 8192 rows * 128 threads
  int row = tid >> 7;
  int sub = tid & 127;
  int h  = sub >> 3;
  int dl = sub & 7;
  const u16* base = QKV + (size_t)row * (3 * D_MODEL) + h * D_HEAD + dl * 8;
  uint4 qu = *(const uint4*)base;
  uint4 ku = *(const uint4*)(base + D_MODEL);
  float q[8], k[8];
  bf8_to_f32(qu, q); bf8_to_f32(ku, k);
  float s = 0.f;
  #pragma unroll
  for (int i = 0; i < 8; ++i) s = fmaf(q[i], k[i], s);
  s += __shfl_xor(s, 1);
  s += __shfl_xor(s, 2);
  s += __shfl_xor(s, 4);
  s *= 0.125f;
  if (dl == 0) S[(size_t)row * N_HEADS + h] = 1.f / (1.f + __expf(-s));
}

// ---- launch ----------------------------------------------------------------
extern "C" void kernel_launch(void* const* d_in, const int* in_sizes, int n_in,
                              void* d_out, int out_size, void* d_ws, size_t ws_size,
                              hipStream_t stream) {
  const float* hs = (const float*)d_in[0];
  const float* Wq = (const float*)d_in[3];
  const float* Wk = (const float*)d_in[4];
  const float* Wv = (const float*)d_in[5];
  const float* Wo = (const float*)d_in[6];
  // d_in[1,2,7,8,9] dead (fast-weight state identically zero).

  const int M = BATCH * SEQ_T;  // 8192
  char* ws = (char*)d_ws;
  u16*  Xb   = (u16*)ws;                    // [8192][1024] bf16 (16 MB)
  u16*  Wb   = (u16*)(ws + (16u << 20));    // [4][1024][1024] bf16 q,k,v,o (8 MB)
  u16*  QKVb = (u16*)(ws + (24u << 20));    // [8192][3072] bf16 (48 MB)
  float* Sb  = (float*)(ws + (72u << 20));  // [8192][16] f32 (512 KB)
  float* out = (float*)d_out;

  cast_kernel<<<12288, 256, 0, stream>>>(hs, Wq, Wk, Wv, Wo, Xb, Wb);
  gemm_bt_kernel<true, false><<<dim3(24, 64), 256, 0, stream>>>(
      Xb, Wb, nullptr, QKVb, M, 3 * D_MODEL, D_MODEL, D_MODEL);
  score_kernel<<<4096, 256, 0, stream>>>(QKVb, Sb);
  gemm_bt_kernel<false, true><<<dim3(8, 64), 256, 0, stream>>>(
      QKVb + 2 * D_MODEL, Wb + 3u * 1048576u, Sb, out, M, D_MODEL, D_MODEL, 3 * D_MODEL);
}

// Round 4
// 209.356 us; speedup vs baseline: 1.0416x; 1.0416x over previous
//
#include <hip/hip_runtime.h>
#include <hip/hip_bf16.h>
#include <stdint.h>

// CortexBlock — reference collapses (U,V start at 0; update is multiplicative
// in the state, so the fast-weight path is identically 0):
//   y[row,h,:] = sigmoid((q_h.k_h)/8) * v_h ;  out = y @ Wo^T
// q,k never leave the QKV GEMM: Wq/Wk rows are interleaved at 16-col
// granularity so each wave fragment holds matching (q_d, k_d) pairs; the
// score is computed in the GEMM epilogue and only S [8192x16] is written.
#define D_MODEL 1024
#define N_HEADS 16
#define D_HEAD  64
#define SEQ_T   2048
#define BATCH   4

typedef unsigned short u16;
typedef __bf16 bf16x8 __attribute__((ext_vector_type(8)));
typedef float  f32x4  __attribute__((ext_vector_type(4)));

// ---- helpers ---------------------------------------------------------------
__device__ __forceinline__ u16 f2bf(float x) {  // RNE f32->bf16
  unsigned u = __float_as_uint(x);
  u += 0x7fffu + ((u >> 16) & 1u);
  return (u16)(u >> 16);
}
__device__ __forceinline__ unsigned pk2(float a, float b) {
  return (unsigned)f2bf(a) | ((unsigned)f2bf(b) << 16);
}
__device__ __forceinline__ unsigned scale2(unsigned p, float s) {
  float lo = __uint_as_float(p << 16) * s;
  float hi = __uint_as_float(p & 0xffff0000u) * s;
  return pk2(lo, hi);
}

// ---- fused cast fp32 -> bf16 with weight-row remap -------------------------
// Wb rows: [0,2048): qk-interleaved: row h*128 + jj*16 + l  (jj=0..7) =
//   (jj odd ? Wk : Wq)[h*64 + (jj>>1)*16 + l];  [2048,3072): Wv; [3072,4096): Wo.
__global__ __launch_bounds__(256) void cast_kernel(const float* __restrict__ hs,
                                                   const float* __restrict__ wq,
                                                   const float* __restrict__ wk,
                                                   const float* __restrict__ wv,
                                                   const float* __restrict__ wo,
                                                   u16* __restrict__ Xb,
                                                   u16* __restrict__ Wb) {
  int i = blockIdx.x * 256 + threadIdx.x;  // float4 units
  const float* src; u16* dst; int soff, doff;
  if (i < (2 << 20)) {                     // X: 2M float4
    src = hs; dst = Xb; soff = i; doff = i;
  } else {
    int j = i - (2 << 20);                 // W: 1M float4
    int R = j >> 8;                        // dest row (block-uniform)
    int col4 = j & 255;
    int srow;
    if (R < 2048) {
      int h = R >> 7, c = R & 127, jj = c >> 4, l = c & 15;
      srow = h * 64 + (jj >> 1) * 16 + l;
      src = (jj & 1) ? wk : wq;
    } else if (R < 3072) { src = wv; srow = R - 2048; }
    else                 { src = wo; srow = R - 3072; }
    dst = Wb; soff = srow * 256 + col4; doff = R * 256 + col4;
  }
  float4 v = ((const float4*)src)[soff];
  uint2 o; o.x = pk2(v.x, v.y); o.y = pk2(v.z, v.w);
  ((uint2*)dst)[doff] = o;
}

// ---- QKV GEMM with fused score ---------------------------------------------
// C[M, 3072-equivalent] = X[M,1024] * Wb[qk|v][.,1024]^T. 128x128 tile,
// 4 waves (2x2 of 64x64), BK=32. Register staging (global->reg prefetch
// overlapped with MFMA, reg->LDS at the barrier) + XOR chunk swizzle
// (chunk ^= (row>>1)&3) -> conflict-free ds_read_b128/ds_write_b128.
// bn<16: head-tile -> score epilogue (writes only S). bn>=16: v-tile -> Vb.
__global__ __launch_bounds__(256) void gemm_qkv_kernel(const u16* __restrict__ A,
                                                       const u16* __restrict__ B,
                                                       u16* __restrict__ Vb,
                                                       float* __restrict__ S,
                                                       int M) {
  constexpr int K = D_MODEL;
  __shared__ u16 As[128 * 32];
  __shared__ u16 Bs[128 * 32];
  const int tid  = threadIdx.x;
  const int lane = tid & 63;
  const int wave = tid >> 6;
  const int wm = (wave >> 1) * 64;
  const int wn = (wave & 1) * 64;
  const int bm = blockIdx.y * 128;
  const int bn = blockIdx.x;
  const int quad = lane >> 4;
  const int l16  = lane & 15;
  const int rchunk = quad ^ ((l16 >> 1) & 3);  // fragment read chunk

  // staging: thread -> rows lr, lr+64; chunk tid&3; swizzled LDS chunk
  const int lr = tid >> 2;
  const int lch = tid & 3;
  const int wch = lch ^ ((lr >> 1) & 3);
  const u16* Ap0 = A + (size_t)(bm + lr) * K + lch * 8;
  const u16* Ap1 = Ap0 + (size_t)64 * K;
  const u16* Bp0 = B + (size_t)(bn * 128 + lr) * K + lch * 8;
  const u16* Bp1 = Bp0 + (size_t)64 * K;
  u16* Aw0 = As + lr * 32 + wch * 8;
  u16* Aw1 = Aw0 + 64 * 32;
  u16* Bw0 = Bs + lr * 32 + wch * 8;
  u16* Bw1 = Bw0 + 64 * 32;

  f32x4 acc[4][4];
  #pragma unroll
  for (int i = 0; i < 4; ++i)
    #pragma unroll
    for (int j = 0; j < 4; ++j) acc[i][j] = (f32x4){0.f, 0.f, 0.f, 0.f};

  uint4 a0 = *(const uint4*)Ap0;
  uint4 a1 = *(const uint4*)Ap1;
  uint4 b0 = *(const uint4*)Bp0;
  uint4 b1 = *(const uint4*)Bp1;

  for (int k0 = 0; k0 < K; k0 += 32) {
    __syncthreads();
    *(uint4*)Aw0 = a0;
    *(uint4*)Aw1 = a1;
    *(uint4*)Bw0 = b0;
    *(uint4*)Bw1 = b1;
    __syncthreads();
    if (k0 + 32 < K) {  // prefetch next chunk; latency hidden by MFMAs
      a0 = *(const uint4*)(Ap0 + k0 + 32);
      a1 = *(const uint4*)(Ap1 + k0 + 32);
      b0 = *(const uint4*)(Bp0 + k0 + 32);
      b1 = *(const uint4*)(Bp1 + k0 + 32);
    }
    bf16x8 af[4], bfr[4];
    #pragma unroll
    for (int i = 0; i < 4; ++i)
      af[i] = *(const bf16x8*)(As + (wm + i * 16 + l16) * 32 + rchunk * 8);
    #pragma unroll
    for (int j = 0; j < 4; ++j)
      bfr[j] = *(const bf16x8*)(Bs + (wn + j * 16 + l16) * 32 + rchunk * 8);
    #pragma unroll
    for (int i = 0; i < 4; ++i)
      #pragma unroll
      for (int j = 0; j < 4; ++j)
        acc[i][j] = __builtin_amdgcn_mfma_f32_16x16x32_bf16(af[i], bfr[j], acc[i][j], 0, 0, 0);
  }

  if (bn < N_HEADS) {
    // score epilogue: cols jj*16+l <-> (jj odd ? k : q)[d=(jj>>1)*16+l].
    // acc[i][j] (j even) pairs with acc[i][j+1]: q_d * k_d, same lane/row.
    float part[4][4];
    #pragma unroll
    for (int i = 0; i < 4; ++i)
      #pragma unroll
      for (int e = 0; e < 4; ++e)
        part[i][e] = acc[i][0][e] * acc[i][1][e] + acc[i][2][e] * acc[i][3][e];
    #pragma unroll
    for (int m = 1; m <= 8; m <<= 1)
      #pragma unroll
      for (int i = 0; i < 4; ++i)
        #pragma unroll
        for (int e = 0; e < 4; ++e)
          part[i][e] += __shfl_xor(part[i][e], m);  // reduce over l16
    __syncthreads();
    float* Sp = (float*)As;  // [128][2]
    if (l16 == 0) {
      #pragma unroll
      for (int i = 0; i < 4; ++i)
        #pragma unroll
        for (int e = 0; e < 4; ++e)
          Sp[(wm + i * 16 + quad * 4 + e) * 2 + (wave & 1)] = part[i][e];
    }
    __syncthreads();
    if (tid < 128) {
      float s = (Sp[tid * 2] + Sp[tid * 2 + 1]) * 0.125f;  // 1/sqrt(64)
      S[(size_t)(bm + tid) * N_HEADS + bn] = 1.f / (1.f + __expf(-s));
    }
  } else {
    const int cb = (bn - N_HEADS) * 128;
    #pragma unroll
    for (int i = 0; i < 4; ++i)
      #pragma unroll
      for (int j = 0; j < 4; ++j)
        #pragma unroll
        for (int e = 0; e < 4; ++e) {
          int row = bm + wm + i * 16 + quad * 4 + e;
          int col = cb + wn + j * 16 + l16;
          Vb[(size_t)row * D_MODEL + col] = f2bf(acc[i][j][e]);
        }
  }
}

// ---- out GEMM: out[M,1024] = (S(row,head)*V)[M,1024] * Wo[1024,1024]^T -----
__global__ __launch_bounds__(256) void gemm_out_kernel(const u16* __restrict__ A,
                                                       const u16* __restrict__ B,
                                                       const float* __restrict__ S,
                                                       float* __restrict__ C,
                                                       int M) {
  constexpr int K = D_MODEL, N = D_MODEL;
  __shared__ u16 As[128 * 32];
  __shared__ u16 Bs[128 * 32];
  const int tid  = threadIdx.x;
  const int lane = tid & 63;
  const int wave = tid >> 6;
  const int wm = (wave >> 1) * 64;
  const int wn = (wave & 1) * 64;
  const int bm = blockIdx.y * 128;
  const int bn = blockIdx.x * 128;
  const int quad = lane >> 4;
  const int l16  = lane & 15;
  const int rchunk = quad ^ ((l16 >> 1) & 3);

  const int lr = tid >> 2;
  const int lch = tid & 3;
  const int wch = lch ^ ((lr >> 1) & 3);
  const u16* Ap0 = A + (size_t)(bm + lr) * K + lch * 8;
  const u16* Ap1 = Ap0 + (size_t)64 * K;
  const u16* Bp0 = B + (size_t)(bn + lr) * K + lch * 8;
  const u16* Bp1 = Bp0 + (size_t)64 * K;
  u16* Aw0 = As + lr * 32 + wch * 8;
  u16* Aw1 = Aw0 + 64 * 32;
  u16* Bw0 = Bs + lr * 32 + wch * 8;
  u16* Bw1 = Bw0 + 64 * 32;
  const float* Sp0 = S + (size_t)(bm + lr) * N_HEADS;
  const float* Sp1 = Sp0 + (size_t)64 * N_HEADS;

  f32x4 acc[4][4];
  #pragma unroll
  for (int i = 0; i < 4; ++i)
    #pragma unroll
    for (int j = 0; j < 4; ++j) acc[i][j] = (f32x4){0.f, 0.f, 0.f, 0.f};

  uint4 a0 = *(const uint4*)Ap0;
  uint4 a1 = *(const uint4*)Ap1;
  uint4 b0 = *(const uint4*)Bp0;
  uint4 b1 = *(const uint4*)Bp1;
  float rs0 = Sp0[0], rs1 = Sp1[0];

  for (int k0 = 0; k0 < K; k0 += 32) {
    __syncthreads();
    uint4 w0, w1;
    w0.x = scale2(a0.x, rs0); w0.y = scale2(a0.y, rs0);
    w0.z = scale2(a0.z, rs0); w0.w = scale2(a0.w, rs0);
    w1.x = scale2(a1.x, rs1); w1.y = scale2(a1.y, rs1);
    w1.z = scale2(a1.z, rs1); w1.w = scale2(a1.w, rs1);
    *(uint4*)Aw0 = w0;
    *(uint4*)Aw1 = w1;
    *(uint4*)Bw0 = b0;
    *(uint4*)Bw1 = b1;
    __syncthreads();
    if (k0 + 32 < K) {
      a0 = *(const uint4*)(Ap0 + k0 + 32);
      a1 = *(const uint4*)(Ap1 + k0 + 32);
      b0 = *(const uint4*)(Bp0 + k0 + 32);
      b1 = *(const uint4*)(Bp1 + k0 + 32);
      rs0 = Sp0[(k0 + 32) >> 6];  // head = k/64
      rs1 = Sp1[(k0 + 32) >> 6];
    }
    bf16x8 af[4], bfr[4];
    #pragma unroll
    for (int i = 0; i < 4; ++i)
      af[i] = *(const bf16x8*)(As + (wm + i * 16 + l16) * 32 + rchunk * 8);
    #pragma unroll
    for (int j = 0; j < 4; ++j)
      bfr[j] = *(const bf16x8*)(Bs + (wn + j * 16 + l16) * 32 + rchunk * 8);
    #pragma unroll
    for (int i = 0; i < 4; ++i)
      #pragma unroll
      for (int j = 0; j < 4; ++j)
        acc[i][j] = __builtin_amdgcn_mfma_f32_16x16x32_bf16(af[i], bfr[j], acc[i][j], 0, 0, 0);
  }

  #pragma unroll
  for (int i = 0; i < 4; ++i)
    #pragma unroll
    for (int j = 0; j < 4; ++j)
      #pragma unroll
      for (int e = 0; e < 4; ++e) {
        int row = bm + wm + i * 16 + quad * 4 + e;
        int col = bn + wn + j * 16 + l16;
        C[(size_t)row * N + col] = acc[i][j][e];
      }
}

// ---- launch ----------------------------------------------------------------
extern "C" void kernel_launch(void* const* d_in, const int* in_sizes, int n_in,
                              void* d_out, int out_size, void* d_ws, size_t ws_size,
                              hipStream_t stream) {
  const float* hs = (const float*)d_in[0];
  const float* Wq = (const float*)d_in[3];
  const float* Wk = (const float*)d_in[4];
  const float* Wv = (const float*)d_in[5];
  const float* Wo = (const float*)d_in[6];
  // d_in[1,2,7,8,9] dead (fast-weight state identically zero).

  const int M = BATCH * SEQ_T;  // 8192
  char* ws = (char*)d_ws;
  u16*  Xb = (u16*)ws;                     // [8192][1024] bf16 (16 MB)
  u16*  Wb = (u16*)(ws + (16u << 20));     // [4096][1024] bf16 qk|v|o (8 MB)
  u16*  Vb = (u16*)(ws + (24u << 20));     // [8192][1024] bf16 (16 MB)
  float* Sb = (float*)(ws + (40u << 20));  // [8192][16] f32 (512 KB)
  float* out = (float*)d_out;

  cast_kernel<<<12288, 256, 0, stream>>>(hs, Wq, Wk, Wv, Wo, Xb, Wb);
  gemm_qkv_kernel<<<dim3(24, 64), 256, 0, stream>>>(Xb, Wb, Vb, Sb, M);
  gemm_out_kernel<<<dim3(8, 64), 256, 0, stream>>>(
      Vb, Wb + (size_t)3072 * D_MODEL, Sb, out, M);
}